// Round 5
// baseline (6396.464 us; speedup 1.0000x reference)
//
#include <hip/hip_runtime.h>
#include <hip/hip_bf16.h>
#include <math.h>

#define SEQ 4096
#define D 256
#define H 8
#define DH 32
#define B 8
#define NL 4
#define NH 2
#define NTOK (B*SEQ)   // 32768

// ---------------- embedding + posenc -> x1, x2 ----------------
__global__ __launch_bounds__(256) void k_embed(const int* __restrict__ x,
    const float* __restrict__ emb, const float* __restrict__ pos,
    float* __restrict__ x1, float* __restrict__ x2) {
  int t = blockIdx.x; int d = threadIdx.x;
  int s = t & (SEQ - 1);
  int tok = x[t];
  float v = emb[tok * D + d] + pos[(size_t)s * D + d];
  x1[(size_t)t * D + d] = v;
  x2[(size_t)t * D + d] = v;
}

// ---------------- layernorm (wave per row) ----------------
__global__ __launch_bounds__(256) void k_ln(const float* __restrict__ X,
    const float* __restrict__ g, const float* __restrict__ bta,
    float* __restrict__ Y) {
  int lane = threadIdx.x & 63, wv = threadIdx.x >> 6;
  int row = blockIdx.x * 4 + wv;
  const float* xr = X + (size_t)row * D;
  float v[4]; float s = 0.f;
  #pragma unroll
  for (int j = 0; j < 4; j++) { v[j] = xr[lane + 64 * j]; s += v[j]; }
  #pragma unroll
  for (int off = 32; off; off >>= 1) s += __shfl_xor(s, off);
  float m = s * (1.0f / D);
  float vs = 0.f;
  #pragma unroll
  for (int j = 0; j < 4; j++) { float d0 = v[j] - m; vs += d0 * d0; }
  #pragma unroll
  for (int off = 32; off; off >>= 1) vs += __shfl_xor(vs, off);
  float inv = rsqrtf(vs * (1.0f / D) + 1e-5f);
  float* yr = Y + (size_t)row * D;
  #pragma unroll
  for (int j = 0; j < 4; j++) {
    int d0 = lane + 64 * j;
    yr[d0] = (v[j] - m) * inv * g[d0] + bta[d0];
  }
}

__device__ __forceinline__ float gelu_f(float x) {
  float x3 = x * x * x;
  return 0.5f * x * (1.0f + tanhf(0.7978845608028654f * (x + 0.044715f * x3)));
}

// ---------------- generic f32 GEMM, 64x64 tile, BK=16 ----------------
// MODE: 1 = store f32 to (b,h,s,dh) head layout, 2 = gelu(acc+bias) f32 store,
//       3 = C += acc (+bias if non-null)
template<int MODE>
__global__ __launch_bounds__(256) void k_gemm(const float* __restrict__ A,
    const float* __restrict__ Bm, float* __restrict__ C,
    const float* __restrict__ bias, int M, int N, int K,
    int lda, int ldb, int ldc) {
  __shared__ float As[16][68];   // transposed: As[k][m]
  __shared__ float Bs[16][68];
  int tid = threadIdx.x;
  int tx = tid & 15, ty = tid >> 4;
  int row0 = blockIdx.y * 64, col0 = blockIdx.x * 64;
  int arow = tid >> 2, ac4 = tid & 3;
  int brow = tid >> 4, bc4 = tid & 15;
  float acc[4][4] = {};
  for (int k0 = 0; k0 < K; k0 += 16) {
    float4 av = *(const float4*)(A + (size_t)(row0 + arow) * lda + k0 + ac4 * 4);
    float4 bv = *(const float4*)(Bm + (size_t)(k0 + brow) * ldb + col0 + bc4 * 4);
    __syncthreads();
    As[ac4 * 4 + 0][arow] = av.x;
    As[ac4 * 4 + 1][arow] = av.y;
    As[ac4 * 4 + 2][arow] = av.z;
    As[ac4 * 4 + 3][arow] = av.w;
    *(float4*)&Bs[brow][bc4 * 4] = bv;
    __syncthreads();
    #pragma unroll
    for (int kk = 0; kk < 16; ++kk) {
      float4 a = *(float4*)&As[kk][ty * 4];
      float4 b = *(float4*)&Bs[kk][tx * 4];
      float ar[4] = {a.x, a.y, a.z, a.w};
      float br[4] = {b.x, b.y, b.z, b.w};
      #pragma unroll
      for (int i = 0; i < 4; i++)
        #pragma unroll
        for (int j = 0; j < 4; j++)
          acc[i][j] = fmaf(ar[i], br[j], acc[i][j]);
    }
  }
  #pragma unroll
  for (int i = 0; i < 4; i++) {
    int gr = row0 + ty * 4 + i;
    #pragma unroll
    for (int j = 0; j < 4; j++) {
      int gc = col0 + tx * 4 + j;
      float vv = acc[i][j];
      if constexpr (MODE == 1) {
        int b0 = gr >> 12, s0 = gr & 4095, h0 = gc >> 5, d0 = gc & 31;
        C[((size_t)(b0 * H + h0) * SEQ + s0) * DH + d0] = vv;
      } else if constexpr (MODE == 2) {
        C[(size_t)gr * ldc + gc] = gelu_f(vv + bias[gc]);
      } else {
        float add = bias ? bias[gc] : 0.f;
        C[(size_t)gr * ldc + gc] += vv + add;
      }
    }
  }
}

// ---------------- LSH bucket + stable counting sort ----------------
__global__ __launch_bounds__(256) void k_hash(const float* __restrict__ qk,
    const float* __restrict__ rot, int* __restrict__ st) {
  __shared__ float rs[32][33];
  __shared__ int sb[SEQ];
  __shared__ int hist[64];
  __shared__ int start[64];
  int tid = threadIdx.x;
  int bh = blockIdx.x >> 1, n = blockIdx.x & 1;
  const float* rotn = rot + n * DH * 32;
  for (int i = tid; i < 1024; i += 256) rs[i >> 5][i & 31] = rotn[i];
  if (tid < 64) hist[tid] = 0;
  __syncthreads();
  const float* qkb = qk + (size_t)bh * SEQ * DH;
  for (int s = tid; s < SEQ; s += 256) {
    float q[32];
    const float* qr = qkb + (size_t)s * DH;
    #pragma unroll
    for (int d = 0; d < 32; d += 4) {
      float4 t4 = *(const float4*)(qr + d);
      q[d] = t4.x; q[d + 1] = t4.y; q[d + 2] = t4.z; q[d + 3] = t4.w;
    }
    float bp = -1e30f, bn = -1e30f; int bpi = 0, bni = 0;
    for (int j = 0; j < 32; j++) {
      float rv = 0.f;
      #pragma unroll
      for (int d = 0; d < 32; d++) rv = fmaf(q[d], rs[d][j], rv);
      if (rv > bp) { bp = rv; bpi = j; }
      if (-rv > bn) { bn = -rv; bni = j; }
    }
    sb[s] = (bp >= bn) ? bpi : (bni + 32);
  }
  __syncthreads();
  for (int s = tid; s < SEQ; s += 256) atomicAdd(&hist[sb[s]], 1);
  __syncthreads();
  if (tid == 0) {
    int acc = 0;
    for (int j = 0; j < 64; j++) { start[j] = acc; acc += hist[j]; }
  }
  __syncthreads();
  if (tid < 64) {
    int j = tid;
    int* outp = st + (size_t)blockIdx.x * SEQ;
    int pos = start[j];
    for (int p = 0; p < SEQ; p++) if (sb[p] == j) outp[pos++] = p;
  }
}

// ---------------- chunked attention, hash half NHALF ----------------
// grid = B*H*64 chunks. NHALF=0: write o0/lse0. NHALF=1: compute o1/lse1 and
// combine with hash-0 result in place (prev kernel launch ordering guarantees
// o_acc/lg complete). Look-back wraps across the hash boundary (c-1 mod 128).
template<int NHALF>
__global__ __launch_bounds__(256) void k_attn(const float* __restrict__ qk,
    const float* __restrict__ v, const int* __restrict__ st,
    float* __restrict__ o_acc, float* __restrict__ lg) {
  __shared__ float qs[64][36];
  __shared__ float vs[128][36];
  __shared__ float dots[64][129];
  __shared__ float lse_s[64];
  __shared__ int stq[64];
  __shared__ int stk[128];
  int tid = threadIdx.x;
  int bh = blockIdx.x >> 6, cl = blockIdx.x & 63;
  int c = NHALF * 64 + cl;
  int pc = (c + 127) & 127, pn = pc >> 6;
  const int* stb = st + (size_t)bh * 2 * SEQ;
  if (tid < 64) {
    int q0 = stb[NHALF * SEQ + cl * 64 + tid];
    stq[tid] = q0; stk[tid] = q0;
  } else if (tid < 128) {
    int kk = tid - 64;
    stk[64 + kk] = stb[pn * SEQ + (pc & 63) * 64 + kk];
  }
  __syncthreads();
  const float* qkb = qk + (size_t)bh * SEQ * DH;
  const float* vb  = v  + (size_t)bh * SEQ * DH;
  for (int idx = tid; idx < 512; idx += 256) {
    int r = idx >> 3, j = idx & 7;
    *(float4*)&qs[r][j * 4] = *(const float4*)(qkb + (size_t)stq[r] * DH + j * 4);
  }
  for (int idx = tid; idx < 1024; idx += 256) {
    int r = idx >> 3, j = idx & 7;
    *(float4*)&vs[r][j * 4] = *(const float4*)(vb + (size_t)stk[r] * DH + j * 4);
  }
  int col = tid & 127;
  int rh = tid >> 7;
  float4 kf[8];
  int kpos = stk[col];
  {
    const float* kr = qkb + (size_t)kpos * DH;
    float nrm = 0.f;
    #pragma unroll
    for (int j = 0; j < 8; j++) {
      kf[j] = *(const float4*)(kr + j * 4);
      nrm += kf[j].x * kf[j].x + kf[j].y * kf[j].y + kf[j].z * kf[j].z + kf[j].w * kf[j].w;
    }
    float sc = 0.17677669529663687f / fmaxf(sqrtf(nrm), 1e-6f);
    #pragma unroll
    for (int j = 0; j < 8; j++) { kf[j].x *= sc; kf[j].y *= sc; kf[j].z *= sc; kf[j].w *= sc; }
  }
  __syncthreads();
  for (int r0 = 0; r0 < 32; ++r0) {
    int r = rh * 32 + r0;
    float dsum = 0.f;
    #pragma unroll
    for (int j = 0; j < 8; j++) {
      float4 qv = *(float4*)&qs[r][j * 4];
      dsum = fmaf(qv.x, kf[j].x, dsum);
      dsum = fmaf(qv.y, kf[j].y, dsum);
      dsum = fmaf(qv.z, kf[j].z, dsum);
      dsum = fmaf(qv.w, kf[j].w, dsum);
    }
    int sq = stq[r];
    float dd = dsum;
    if (sq == kpos) dd = -1e5f;
    else if (sq < kpos) dd = -1e9f;
    dots[r][col] = dd;
  }
  __syncthreads();
  int lane = tid & 63, wv = tid >> 6;
  for (int rr = 0; rr < 16; ++rr) {
    int r = wv * 16 + rr;
    float d0 = dots[r][lane], d1 = dots[r][lane + 64];
    float m = fmaxf(d0, d1);
    #pragma unroll
    for (int off = 32; off; off >>= 1) m = fmaxf(m, __shfl_xor(m, off));
    float e0 = expf(d0 - m), e1 = expf(d1 - m);
    float ssum = e0 + e1;
    #pragma unroll
    for (int off = 32; off; off >>= 1) ssum += __shfl_xor(ssum, off);
    float inv = 1.0f / ssum;
    dots[r][lane] = e0 * inv;
    dots[r][lane + 64] = e1 * inv;
    if (lane == 0) lse_s[r] = m + logf(ssum);
  }
  __syncthreads();
  int r = tid >> 2, dq = (tid & 3) << 3;
  float4 a0 = make_float4(0, 0, 0, 0), a1 = make_float4(0, 0, 0, 0);
  for (int cc = 0; cc < 128; ++cc) {
    float p = dots[r][cc];
    float4 v0 = *(float4*)&vs[cc][dq];
    float4 v1 = *(float4*)&vs[cc][dq + 4];
    a0.x = fmaf(p, v0.x, a0.x); a0.y = fmaf(p, v0.y, a0.y);
    a0.z = fmaf(p, v0.z, a0.z); a0.w = fmaf(p, v0.w, a0.w);
    a1.x = fmaf(p, v1.x, a1.x); a1.y = fmaf(p, v1.y, a1.y);
    a1.z = fmaf(p, v1.z, a1.z); a1.w = fmaf(p, v1.w, a1.w);
  }
  int pos = stq[r];
  int b0 = bh >> 3, h0 = bh & 7;
  float* orow = o_acc + ((size_t)b0 * SEQ + pos) * D + h0 * DH + dq;
  if constexpr (NHALF == 0) {
    *(float4*)orow = a0;
    *(float4*)(orow + 4) = a1;
  } else {
    float l0 = lg[(size_t)bh * SEQ + pos];
    float l1 = lse_s[r];
    float m = fmaxf(l0, l1);
    float w0 = expf(l0 - m), w1 = expf(l1 - m);
    float inv = 1.0f / (w0 + w1);
    float4 o0 = *(float4*)orow;
    float4 o1 = *(float4*)(orow + 4);
    o0.x = (w0 * o0.x + w1 * a0.x) * inv;
    o0.y = (w0 * o0.y + w1 * a0.y) * inv;
    o0.z = (w0 * o0.z + w1 * a0.z) * inv;
    o0.w = (w0 * o0.w + w1 * a0.w) * inv;
    o1.x = (w0 * o1.x + w1 * a1.x) * inv;
    o1.y = (w0 * o1.y + w1 * a1.y) * inv;
    o1.z = (w0 * o1.z + w1 * a1.z) * inv;
    o1.w = (w0 * o1.w + w1 * a1.w) * inv;
    *(float4*)orow = o0;
    *(float4*)(orow + 4) = o1;
  }
  if constexpr (NHALF == 0) {
    if (tid < 64) lg[(size_t)bh * SEQ + stq[tid]] = lse_s[tid];
  }
}

// ---------------- final classifier ----------------
__global__ __launch_bounds__(128) void k_initout(const float* __restrict__ bf,
                                                 float* __restrict__ outp) {
  int i = threadIdx.x;
  if (i < 80) outp[i] = bf[i % 10];
}

__global__ __launch_bounds__(256) void k_cls(const float* __restrict__ x1,
    const float* __restrict__ x2, const float* __restrict__ Wf,
    float* __restrict__ outp) {
  __shared__ float wsum[4];
  int tid = threadIdx.x;
  size_t ib = (size_t)blockIdx.x * 1024 + tid * 4;
  int lane = tid & 63, wv = tid >> 6;
  for (int b0 = 0; b0 < B; ++b0) {
    const float* p1 = x1 + (size_t)b0 * (SEQ * D) + ib;
    const float* p2 = x2 + (size_t)b0 * (SEQ * D) + ib;
    float4 y1 = *(const float4*)p1;
    float4 y2 = *(const float4*)p2;
    float y[4] = {0.5f * (y1.x + y2.x), 0.5f * (y1.y + y2.y),
                  0.5f * (y1.z + y2.z), 0.5f * (y1.w + y2.w)};
    float acc[10] = {};
    #pragma unroll
    for (int t = 0; t < 4; ++t) {
      const float* wr = Wf + (ib + t) * 10;
      #pragma unroll
      for (int c0 = 0; c0 < 10; ++c0) acc[c0] = fmaf(y[t], wr[c0], acc[c0]);
    }
    #pragma unroll 1
    for (int c0 = 0; c0 < 10; ++c0) {
      float sv = acc[c0];
      #pragma unroll
      for (int off = 32; off; off >>= 1) sv += __shfl_xor(sv, off);
      if (lane == 0) wsum[wv] = sv;
      __syncthreads();
      if (tid == 0) atomicAdd(&outp[b0 * 10 + c0], wsum[0] + wsum[1] + wsum[2] + wsum[3]);
      __syncthreads();
    }
  }
}

extern "C" void kernel_launch(void* const* d_in, const int* in_sizes, int n_in,
                              void* d_out, int out_size, void* d_ws, size_t ws_size,
                              hipStream_t stream) {
  const int*   x    = (const int*)  d_in[0];
  const float* emb  = (const float*)d_in[1];
  const float* pos  = (const float*)d_in[2];
  const float* ln1g = (const float*)d_in[3];
  const float* ln1b = (const float*)d_in[4];
  const float* Wqk  = (const float*)d_in[5];
  const float* Wv   = (const float*)d_in[6];
  const float* Wo   = (const float*)d_in[7];
  const float* ln2g = (const float*)d_in[8];
  const float* ln2b = (const float*)d_in[9];
  const float* W1   = (const float*)d_in[10];
  const float* b1   = (const float*)d_in[11];
  const float* W2   = (const float*)d_in[12];
  const float* b2   = (const float*)d_in[13];
  const float* rot  = (const float*)d_in[14];
  const float* Wf   = (const float*)d_in[15];
  const float* bf   = (const float*)d_in[16];
  float* outp = (float*)d_out;

  const size_t SZ = (size_t)NTOK * D;  // 8,388,608 floats
  // Peak 5*SZ + 3MiB = 163 MiB (ws evidence: 180 MiB ok, 228 MiB crash)
  float* x1  = (float*)d_ws;              // SZ
  float* x2  = x1 + SZ;                   // SZ
  float* tln = x1 + 2 * SZ;               // SZ; o_acc/och alias (dead after QK/V gemms)
  float* och = tln;
  float* qk  = x1 + 3 * SZ;               // SZ
  float* vv  = x1 + 4 * SZ;               // SZ
  float* lg  = x1 + 5 * SZ;               // B*H*SEQ = 262144 floats (hash-0 LSE)
  int*   st  = (int*)(lg + (size_t)B * H * SEQ);  // B*H*NH*SEQ = 524288 ints
  float* mid = qk;                        // 2*SZ at FFN time (qk/vv dead)

  k_embed<<<NTOK, 256, 0, stream>>>(x, emb, pos, x1, x2);
  for (int l = 0; l < NL; ++l) {
    k_ln<<<NTOK / 4, 256, 0, stream>>>(x2, ln1g + l * D, ln1b + l * D, tln);
    k_gemm<1><<<dim3(D / 64, NTOK / 64), 256, 0, stream>>>(
        tln, Wqk + (size_t)l * D * D, qk, nullptr, NTOK, D, D, D, D, 0);
    k_gemm<1><<<dim3(D / 64, NTOK / 64), 256, 0, stream>>>(
        tln, Wv + (size_t)l * D * D, vv, nullptr, NTOK, D, D, D, D, 0);
    k_hash<<<B * H * NH, 256, 0, stream>>>(qk, rot + (size_t)l * NH * DH * 32, st);
    k_attn<0><<<B * H * 64, 256, 0, stream>>>(qk, vv, st, och, lg);
    k_attn<1><<<B * H * 64, 256, 0, stream>>>(qk, vv, st, och, lg);
    k_gemm<3><<<dim3(D / 64, NTOK / 64), 256, 0, stream>>>(
        och, Wo + (size_t)l * D * D, x1, nullptr, NTOK, D, D, D, D, D);
    k_ln<<<NTOK / 4, 256, 0, stream>>>(x1, ln2g + l * D, ln2b + l * D, tln);
    k_gemm<2><<<dim3(1024 / 64, NTOK / 64), 256, 0, stream>>>(
        tln, W1 + (size_t)l * D * 1024, mid, b1 + (size_t)l * 1024,
        NTOK, 1024, D, D, 1024, 1024);
    k_gemm<3><<<dim3(D / 64, NTOK / 64), 256, 0, stream>>>(
        mid, W2 + (size_t)l * 1024 * D, x2, b2 + (size_t)l * D,
        NTOK, D, 1024, 1024, D, D);
  }
  k_initout<<<1, 128, 0, stream>>>(bf, outp);
  k_cls<<<1024, 256, 0, stream>>>(x1, x2, Wf, outp);
}

// Round 10
// 5778.545 us; speedup vs baseline: 1.1069x; 1.1069x over previous
//
#include <hip/hip_runtime.h>
#include <hip/hip_bf16.h>
#include <math.h>

#define SEQ 4096
#define D 256
#define H 8
#define DH 32
#define B 8
#define NL 4
#define NH 2
#define NTOK (B*SEQ)   // 32768

__device__ __forceinline__ float gelu_f(float x) {
  float x3 = x * x * x;
  return 0.5f * x * (1.0f + tanhf(0.7978845608028654f * (x + 0.044715f * x3)));
}

// ---------------- embedding + posenc -> x1, x2 ----------------
__global__ __launch_bounds__(256) void k_embed(const int* __restrict__ x,
    const float* __restrict__ emb, const float* __restrict__ pos,
    float* __restrict__ x1, float* __restrict__ x2) {
  int t = blockIdx.x; int d = threadIdx.x;
  int s = t & (SEQ - 1);
  int tok = x[t];
  float v = emb[tok * D + d] + pos[(size_t)s * D + d];
  x1[(size_t)t * D + d] = v;
  x2[(size_t)t * D + d] = v;
}

// ---------------- layernorm (wave per row) ----------------
__global__ __launch_bounds__(256) void k_ln(const float* __restrict__ X,
    const float* __restrict__ g, const float* __restrict__ bta,
    float* __restrict__ Y) {
  int lane = threadIdx.x & 63, wv = threadIdx.x >> 6;
  int row = blockIdx.x * 4 + wv;
  const float* xr = X + (size_t)row * D;
  float v[4]; float s = 0.f;
  #pragma unroll
  for (int j = 0; j < 4; j++) { v[j] = xr[lane + 64 * j]; s += v[j]; }
  #pragma unroll
  for (int off = 32; off; off >>= 1) s += __shfl_xor(s, off);
  float m = s * (1.0f / D);
  float vs = 0.f;
  #pragma unroll
  for (int j = 0; j < 4; j++) { float d0 = v[j] - m; vs += d0 * d0; }
  #pragma unroll
  for (int off = 32; off; off >>= 1) vs += __shfl_xor(vs, off);
  float inv = rsqrtf(vs * (1.0f / D) + 1e-5f);
  float* yr = Y + (size_t)row * D;
  #pragma unroll
  for (int j = 0; j < 4; j++) {
    int d0 = lane + 64 * j;
    yr[d0] = (v[j] - m) * inv * g[d0] + bta[d0];
  }
}

// ---------------- f32 GEMM: 128x128 tile, BK=16, 8x8 micro-tile ----------------
// A [M,lda] row-major, B [K',ldb] row-major slice. 256 threads.
// MODE 0: store f32 to (b,h,s,dh) head layout. MODE 2: gelu(acc+bias) store.
// MODE 3: C += acc (+bias if non-null).
template<int MODE>
__global__ __launch_bounds__(256) void k_gemm_f32(const float* __restrict__ A,
    const float* __restrict__ Bm, float* __restrict__ C,
    const float* __restrict__ bias, int K, int lda, int ldb, int ldc, int N) {
  __shared__ float As[16][132];   // transposed: As[k][m]
  __shared__ float Bs[16][132];
  int t = threadIdx.x;
  int tx = t & 15, ty = t >> 4;
  int row0 = blockIdx.y * 128, col0 = blockIdx.x * 128;
  int ar = t >> 1, akq = (t & 1) * 8;     // A: 2 threads/row, 8 k each
  int bk = t >> 4, bcq = (t & 15) * 8;    // B: 16 threads/k-row, 8 cols each
  const float* ap = A + (size_t)(row0 + ar) * lda + akq;
  const float* bp = Bm + (size_t)bk * ldb + col0 + bcq;
  float4 a0 = *(const float4*)(ap);
  float4 a1 = *(const float4*)(ap + 4);
  float4 b0 = *(const float4*)(bp);
  float4 b1 = *(const float4*)(bp + 4);
  float acc[8][8] = {};
  for (int k0 = 0; k0 < K; k0 += 16) {
    __syncthreads();
    As[akq + 0][ar] = a0.x; As[akq + 1][ar] = a0.y;
    As[akq + 2][ar] = a0.z; As[akq + 3][ar] = a0.w;
    As[akq + 4][ar] = a1.x; As[akq + 5][ar] = a1.y;
    As[akq + 6][ar] = a1.z; As[akq + 7][ar] = a1.w;
    *(float4*)&Bs[bk][bcq] = b0;
    *(float4*)&Bs[bk][bcq + 4] = b1;
    __syncthreads();
    if (k0 + 16 < K) {  // prefetch next tile into registers (overlaps compute)
      a0 = *(const float4*)(ap + k0 + 16);
      a1 = *(const float4*)(ap + k0 + 20);
      const float* bpk = Bm + (size_t)(k0 + 16 + bk) * ldb + col0 + bcq;
      b0 = *(const float4*)(bpk);
      b1 = *(const float4*)(bpk + 4);
    }
    #pragma unroll
    for (int kk = 0; kk < 16; ++kk) {
      float a[8], b[8];
      *(float4*)&a[0] = *(float4*)&As[kk][ty * 8];
      *(float4*)&a[4] = *(float4*)&As[kk][ty * 8 + 4];
      *(float4*)&b[0] = *(float4*)&Bs[kk][tx * 8];
      *(float4*)&b[4] = *(float4*)&Bs[kk][tx * 8 + 4];
      #pragma unroll
      for (int i = 0; i < 8; i++)
        #pragma unroll
        for (int j = 0; j < 8; j++)
          acc[i][j] = fmaf(a[i], b[j], acc[i][j]);
    }
  }
  #pragma unroll
  for (int i = 0; i < 8; i++) {
    int gr = row0 + ty * 8 + i;
    int gc0 = col0 + tx * 8;
    if constexpr (MODE == 0) {
      // 8 cols lie within one 32-wide head block (gc0 % 32 in {0,8,16,24})
      int b0i = gr >> 12, s0 = gr & 4095, h0 = gc0 >> 5, d0 = gc0 & 31;
      float* dst = C + ((size_t)(b0i * H + h0) * SEQ + s0) * DH + d0;
      *(float4*)dst = *(float4*)&acc[i][0];
      *(float4*)(dst + 4) = *(float4*)&acc[i][4];
    } else if constexpr (MODE == 2) {
      float* dst = C + (size_t)gr * ldc + gc0;
      float o[8];
      #pragma unroll
      for (int j = 0; j < 8; j++) o[j] = gelu_f(acc[i][j] + bias[gc0 + j]);
      *(float4*)dst = *(float4*)&o[0];
      *(float4*)(dst + 4) = *(float4*)&o[4];
    } else {
      float* dst = C + (size_t)gr * ldc + gc0;
      float4 c0 = *(float4*)dst, c1 = *(float4*)(dst + 4);
      float add[8];
      #pragma unroll
      for (int j = 0; j < 8; j++) add[j] = bias ? bias[gc0 + j] : 0.f;
      c0.x += acc[i][0] + add[0]; c0.y += acc[i][1] + add[1];
      c0.z += acc[i][2] + add[2]; c0.w += acc[i][3] + add[3];
      c1.x += acc[i][4] + add[4]; c1.y += acc[i][5] + add[5];
      c1.z += acc[i][6] + add[6]; c1.w += acc[i][7] + add[7];
      *(float4*)dst = c0;
      *(float4*)(dst + 4) = c1;
    }
  }
}

// ---------------- LSH bucket + stable counting sort ----------------
__global__ __launch_bounds__(256) void k_hash(const float* __restrict__ qk,
    const float* __restrict__ rot, int* __restrict__ st) {
  __shared__ float rs[32][33];
  __shared__ int sb[SEQ];
  __shared__ int hist[64];
  __shared__ int start[64];
  int tid = threadIdx.x;
  int bh = blockIdx.x >> 1, n = blockIdx.x & 1;
  const float* rotn = rot + n * DH * 32;
  for (int i = tid; i < 1024; i += 256) rs[i >> 5][i & 31] = rotn[i];
  if (tid < 64) hist[tid] = 0;
  __syncthreads();
  const float* qkb = qk + (size_t)bh * SEQ * DH;
  for (int s = tid; s < SEQ; s += 256) {
    float q[32];
    const float* qr = qkb + (size_t)s * DH;
    #pragma unroll
    for (int d = 0; d < 32; d += 4) {
      float4 t4 = *(const float4*)(qr + d);
      q[d] = t4.x; q[d + 1] = t4.y; q[d + 2] = t4.z; q[d + 3] = t4.w;
    }
    float bp = -1e30f, bn = -1e30f; int bpi = 0, bni = 0;
    for (int j = 0; j < 32; j++) {
      float rv = 0.f;
      #pragma unroll
      for (int d = 0; d < 32; d++) rv = fmaf(q[d], rs[d][j], rv);
      if (rv > bp) { bp = rv; bpi = j; }
      if (-rv > bn) { bn = -rv; bni = j; }
    }
    sb[s] = (bp >= bn) ? bpi : (bni + 32);
  }
  __syncthreads();
  for (int s = tid; s < SEQ; s += 256) atomicAdd(&hist[sb[s]], 1);
  __syncthreads();
  if (tid == 0) {
    int acc = 0;
    for (int j = 0; j < 64; j++) { start[j] = acc; acc += hist[j]; }
  }
  __syncthreads();
  if (tid < 64) {
    int j = tid;
    int* outp = st + (size_t)blockIdx.x * SEQ;
    int pos = start[j];
    for (int p = 0; p < SEQ; p++) if (sb[p] == j) outp[pos++] = p;
  }
}

// ---------------- chunked attention, hash half NHALF ----------------
// NHALF=0: write o0/lse0. NHALF=1: compute o1/lse1 and combine in place.
template<int NHALF>
__global__ __launch_bounds__(256) void k_attn(const float* __restrict__ qk,
    const float* __restrict__ v, const int* __restrict__ st,
    float* __restrict__ o_acc, float* __restrict__ lg) {
  __shared__ float qs[64][36];
  __shared__ float vs[128][36];
  __shared__ float dots[64][129];
  __shared__ float lse_s[64];
  __shared__ int stq[64];
  __shared__ int stk[128];
  int tid = threadIdx.x;
  int bh = blockIdx.x >> 6, cl = blockIdx.x & 63;
  int c = NHALF * 64 + cl;
  int pc = (c + 127) & 127, pn = pc >> 6;
  const int* stb = st + (size_t)bh * 2 * SEQ;
  if (tid < 64) {
    int q0 = stb[NHALF * SEQ + cl * 64 + tid];
    stq[tid] = q0; stk[tid] = q0;
  } else if (tid < 128) {
    int kk = tid - 64;
    stk[64 + kk] = stb[pn * SEQ + (pc & 63) * 64 + kk];
  }
  __syncthreads();
  const float* qkb = qk + (size_t)bh * SEQ * DH;
  const float* vb  = v  + (size_t)bh * SEQ * DH;
  for (int idx = tid; idx < 512; idx += 256) {
    int r = idx >> 3, j = idx & 7;
    *(float4*)&qs[r][j * 4] = *(const float4*)(qkb + (size_t)stq[r] * DH + j * 4);
  }
  for (int idx = tid; idx < 1024; idx += 256) {
    int r = idx >> 3, j = idx & 7;
    *(float4*)&vs[r][j * 4] = *(const float4*)(vb + (size_t)stk[r] * DH + j * 4);
  }
  int col = tid & 127;
  int rh = tid >> 7;
  float4 kf[8];
  int kpos = stk[col];
  {
    const float* kr = qkb + (size_t)kpos * DH;
    float nrm = 0.f;
    #pragma unroll
    for (int j = 0; j < 8; j++) {
      kf[j] = *(const float4*)(kr + j * 4);
      nrm += kf[j].x * kf[j].x + kf[j].y * kf[j].y + kf[j].z * kf[j].z + kf[j].w * kf[j].w;
    }
    float sc = 0.17677669529663687f / fmaxf(sqrtf(nrm), 1e-6f);
    #pragma unroll
    for (int j = 0; j < 8; j++) { kf[j].x *= sc; kf[j].y *= sc; kf[j].z *= sc; kf[j].w *= sc; }
  }
  __syncthreads();
  for (int r0 = 0; r0 < 32; ++r0) {
    int r = rh * 32 + r0;
    float dsum = 0.f;
    #pragma unroll
    for (int j = 0; j < 8; j++) {
      float4 qv = *(float4*)&qs[r][j * 4];
      dsum = fmaf(qv.x, kf[j].x, dsum);
      dsum = fmaf(qv.y, kf[j].y, dsum);
      dsum = fmaf(qv.z, kf[j].z, dsum);
      dsum = fmaf(qv.w, kf[j].w, dsum);
    }
    int sq = stq[r];
    float dd = dsum;
    if (sq == kpos) dd = -1e5f;
    else if (sq < kpos) dd = -1e9f;
    dots[r][col] = dd;
  }
  __syncthreads();
  int lane = tid & 63, wv = tid >> 6;
  for (int rr = 0; rr < 16; ++rr) {
    int r = wv * 16 + rr;
    float d0 = dots[r][lane], d1 = dots[r][lane + 64];
    float m = fmaxf(d0, d1);
    #pragma unroll
    for (int off = 32; off; off >>= 1) m = fmaxf(m, __shfl_xor(m, off));
    float e0 = expf(d0 - m), e1 = expf(d1 - m);
    float ssum = e0 + e1;
    #pragma unroll
    for (int off = 32; off; off >>= 1) ssum += __shfl_xor(ssum, off);
    float inv = 1.0f / ssum;
    dots[r][lane] = e0 * inv;
    dots[r][lane + 64] = e1 * inv;
    if (lane == 0) lse_s[r] = m + logf(ssum);
  }
  __syncthreads();
  int r = tid >> 2, dq = (tid & 3) << 3;
  float4 a0 = make_float4(0, 0, 0, 0), a1 = make_float4(0, 0, 0, 0);
  for (int cc = 0; cc < 128; ++cc) {
    float p = dots[r][cc];
    float4 v0 = *(float4*)&vs[cc][dq];
    float4 v1 = *(float4*)&vs[cc][dq + 4];
    a0.x = fmaf(p, v0.x, a0.x); a0.y = fmaf(p, v0.y, a0.y);
    a0.z = fmaf(p, v0.z, a0.z); a0.w = fmaf(p, v0.w, a0.w);
    a1.x = fmaf(p, v1.x, a1.x); a1.y = fmaf(p, v1.y, a1.y);
    a1.z = fmaf(p, v1.z, a1.z); a1.w = fmaf(p, v1.w, a1.w);
  }
  int pos = stq[r];
  int b0 = bh >> 3, h0 = bh & 7;
  float* orow = o_acc + ((size_t)b0 * SEQ + pos) * D + h0 * DH + dq;
  if constexpr (NHALF == 0) {
    *(float4*)orow = a0;
    *(float4*)(orow + 4) = a1;
  } else {
    float l0 = lg[(size_t)bh * SEQ + pos];
    float l1 = lse_s[r];
    float m = fmaxf(l0, l1);
    float w0 = expf(l0 - m), w1 = expf(l1 - m);
    float inv = 1.0f / (w0 + w1);
    float4 o0 = *(float4*)orow;
    float4 o1 = *(float4*)(orow + 4);
    o0.x = (w0 * o0.x + w1 * a0.x) * inv;
    o0.y = (w0 * o0.y + w1 * a0.y) * inv;
    o0.z = (w0 * o0.z + w1 * a0.z) * inv;
    o0.w = (w0 * o0.w + w1 * a0.w) * inv;
    o1.x = (w0 * o1.x + w1 * a1.x) * inv;
    o1.y = (w0 * o1.y + w1 * a1.y) * inv;
    o1.z = (w0 * o1.z + w1 * a1.z) * inv;
    o1.w = (w0 * o1.w + w1 * a1.w) * inv;
    *(float4*)orow = o0;
    *(float4*)(orow + 4) = o1;
  }
  if constexpr (NHALF == 0) {
    if (tid < 64) lg[(size_t)bh * SEQ + stq[tid]] = lse_s[tid];
  }
}

// ---------------- final classifier ----------------
__global__ __launch_bounds__(128) void k_initout(const float* __restrict__ bf,
                                                 float* __restrict__ outp) {
  int i = threadIdx.x;
  if (i < 80) outp[i] = bf[i % 10];
}

__global__ __launch_bounds__(256) void k_cls(const float* __restrict__ x1,
    const float* __restrict__ x2, const float* __restrict__ Wf,
    float* __restrict__ outp) {
  __shared__ float part[4][10];
  int tid = threadIdx.x;
  size_t ib = (size_t)blockIdx.x * 1024 + tid * 4;
  int lane = tid & 63, wv = tid >> 6;
  float wf[4][10];
  #pragma unroll
  for (int e = 0; e < 4; e++)
    #pragma unroll
    for (int c = 0; c < 10; c++) wf[e][c] = Wf[(ib + e) * 10 + c];
  for (int b0 = 0; b0 < B; ++b0) {
    float4 y1 = *(const float4*)(x1 + (size_t)b0 * (SEQ * D) + ib);
    float4 y2 = *(const float4*)(x2 + (size_t)b0 * (SEQ * D) + ib);
    float y[4] = {0.5f * (y1.x + y2.x), 0.5f * (y1.y + y2.y),
                  0.5f * (y1.z + y2.z), 0.5f * (y1.w + y2.w)};
    float acc[10] = {};
    #pragma unroll
    for (int e = 0; e < 4; e++)
      #pragma unroll
      for (int c = 0; c < 10; c++) acc[c] = fmaf(y[e], wf[e][c], acc[c]);
    #pragma unroll
    for (int c = 0; c < 10; c++) {
      #pragma unroll
      for (int off = 32; off; off >>= 1) acc[c] += __shfl_xor(acc[c], off);
    }
    if (lane == 0) {
      #pragma unroll
      for (int c = 0; c < 10; c++) part[wv][c] = acc[c];
    }
    __syncthreads();
    if (tid < 10)
      atomicAdd(&outp[b0 * 10 + tid],
                part[0][tid] + part[1][tid] + part[2][tid] + part[3][tid]);
    __syncthreads();
  }
}

extern "C" void kernel_launch(void* const* d_in, const int* in_sizes, int n_in,
                              void* d_out, int out_size, void* d_ws, size_t ws_size,
                              hipStream_t stream) {
  const int*   x    = (const int*)  d_in[0];
  const float* emb  = (const float*)d_in[1];
  const float* pos  = (const float*)d_in[2];
  const float* ln1g = (const float*)d_in[3];
  const float* ln1b = (const float*)d_in[4];
  const float* Wqk  = (const float*)d_in[5];
  const float* Wv   = (const float*)d_in[6];
  const float* Wo   = (const float*)d_in[7];
  const float* ln2g = (const float*)d_in[8];
  const float* ln2b = (const float*)d_in[9];
  const float* W1   = (const float*)d_in[10];
  const float* b1   = (const float*)d_in[11];
  const float* W2   = (const float*)d_in[12];
  const float* b2   = (const float*)d_in[13];
  const float* rot  = (const float*)d_in[14];
  const float* Wf   = (const float*)d_in[15];
  const float* bf   = (const float*)d_in[16];
  float* outp = (float*)d_out;

  const size_t SZ = (size_t)NTOK * D;  // 8,388,608 floats
  // Peak 5*SZ + 3MiB = 163 MiB (proven: 163 ok r5, 180 ok r2, 227 crash r3)
  float* x1  = (float*)d_ws;              // SZ
  float* x2  = x1 + SZ;                   // SZ
  float* tln = x1 + 2 * SZ;               // SZ; och aliases (tln dead after QK/V)
  float* och = tln;
  float* qk  = x1 + 3 * SZ;               // SZ
  float* vv  = x1 + 4 * SZ;               // SZ
  float* lg  = x1 + 5 * SZ;               // B*H*SEQ floats (hash-0 LSE)
  int*   st  = (int*)(lg + (size_t)B * H * SEQ);  // B*H*NH*SEQ ints
  float* mid = qk;  // [NTOK][512] f32 per FFN half = 2*SZ over qk+vv (dead)

  k_embed<<<NTOK, 256, 0, stream>>>(x, emb, pos, x1, x2);
  for (int l = 0; l < NL; ++l) {
    k_ln<<<NTOK / 4, 256, 0, stream>>>(x2, ln1g + l * D, ln1b + l * D, tln);
    k_gemm_f32<0><<<dim3(2, 256), 256, 0, stream>>>(
        tln, Wqk + (size_t)l * D * D, qk, nullptr, 256, 256, 256, 0, 256);
    k_gemm_f32<0><<<dim3(2, 256), 256, 0, stream>>>(
        tln, Wv + (size_t)l * D * D, vv, nullptr, 256, 256, 256, 0, 256);
    k_hash<<<B * H * NH, 256, 0, stream>>>(qk, rot + (size_t)l * NH * DH * 32, st);
    k_attn<0><<<B * H * 64, 256, 0, stream>>>(qk, vv, st, och, lg);
    k_attn<1><<<B * H * 64, 256, 0, stream>>>(qk, vv, st, och, lg);
    k_gemm_f32<3><<<dim3(2, 256), 256, 0, stream>>>(
        och, Wo + (size_t)l * D * D, x1, nullptr, 256, 256, 256, 256, 256);
    k_ln<<<NTOK / 4, 256, 0, stream>>>(x1, ln2g + l * D, ln2b + l * D, tln);
    for (int h = 0; h < 2; ++h) {
      k_gemm_f32<2><<<dim3(4, 256), 256, 0, stream>>>(
          tln, W1 + (size_t)l * D * 1024 + h * 512, mid,
          b1 + (size_t)l * 1024 + h * 512, 256, 256, 1024, 512, 512);
      k_gemm_f32<3><<<dim3(2, 256), 256, 0, stream>>>(
          mid, W2 + (size_t)l * 1024 * D + (size_t)h * 512 * D, x2,
          h == 0 ? b2 + (size_t)l * D : nullptr, 512, 512, 256, 256, 256);
    }
  }
  k_initout<<<1, 128, 0, stream>>>(bf, outp);
  k_cls<<<1024, 256, 0, stream>>>(x1, x2, Wf, outp);
}